// Round 1
// baseline (2646.313 us; speedup 1.0000x reference)
//
#include <hip/hip_runtime.h>

#define NN 262144
#define HH 512
#define CC 32
#define MOMF 0.99f

// ws layout (float offsets)
#define WS_SUMS   0
#define WS_COUNTS 16384
#define WS_UPD    16416
#define WS_KBUF   32800
#define WS_VBUF   49184
#define WS_M      65568
#define WS_SB     196640
#define WS_P      196896
#define WS_ASSIGN 327968

static __device__ __forceinline__ unsigned short f2bf(float f) {
  unsigned int u = __float_as_uint(f);
  u += 0x7FFFu + ((u >> 16) & 1u);   // round-to-nearest-even
  return (unsigned short)(u >> 16);
}
static __device__ __forceinline__ float bf2f(unsigned short s) {
  return __uint_as_float(((unsigned int)s) << 16);
}

// ---------------------------------------------------------------------------
// Kernel 1: nearest-centroid assignment. argmin_c(||c||^2 - 2 x.c)
// 512 thr/block, 1 node/thread, centroids staged fp32 in LDS (64KB).
// ---------------------------------------------------------------------------
__global__ __launch_bounds__(512) void k_assign(const float* __restrict__ x,
                                                const float* __restrict__ cent,
                                                int* __restrict__ assign) {
  __shared__ __align__(16) float cl[CC * HH];   // 64 KB
  __shared__ float cn[CC];
  __shared__ float scratch[512];
  const int tid = threadIdx.x;

  for (int i = tid * 4; i < CC * HH; i += 512 * 4)
    *(float4*)&cl[i] = *(const float4*)&cent[i];
  __syncthreads();

  {
    int c = tid >> 4, kk = tid & 15;
    float p = 0.f;
    for (int m = 0; m < 32; ++m) { float v = cl[c * HH + kk + 16 * m]; p += v * v; }
    scratch[tid] = p;
  }
  __syncthreads();
  if (tid < CC) {
    float s = 0.f;
    for (int m = 0; m < 16; ++m) s += scratch[tid * 16 + m];
    cn[tid] = s;
  }
  __syncthreads();

  const int n = blockIdx.x * 512 + tid;
  float acc[CC];
#pragma unroll
  for (int c = 0; c < CC; ++c) acc[c] = 0.f;
  const float* xr = x + (size_t)n * HH;
  for (int kk = 0; kk < HH; kk += 8) {
    float4 a0 = *(const float4*)&xr[kk];
    float4 a1 = *(const float4*)&xr[kk + 4];
#pragma unroll
    for (int c = 0; c < CC; ++c) {
      float4 c0 = *(const float4*)&cl[c * HH + kk];
      float4 c1 = *(const float4*)&cl[c * HH + kk + 4];
      acc[c] += a0.x * c0.x + a0.y * c0.y + a0.z * c0.z + a0.w * c0.w
              + a1.x * c1.x + a1.y * c1.y + a1.z * c1.z + a1.w * c1.w;
    }
  }
  float best = 3.4e38f; int bi = 0;
#pragma unroll
  for (int c = 0; c < CC; ++c) {
    float s = cn[c] - 2.f * acc[c];
    if (s < best) { best = s; bi = c; }
  }
  assign[n] = bi;
}

// ---------------------------------------------------------------------------
// Kernel 2: segment sums + counts. Wave-per-node, LDS accumulation,
// k = 64*j + lane layout -> 2-way-max LDS bank aliasing on ds_add.
// ---------------------------------------------------------------------------
__global__ __launch_bounds__(256) void k_sums(const float* __restrict__ x,
                                              const int* __restrict__ assign,
                                              float* __restrict__ gsums,
                                              float* __restrict__ gcounts) {
  __shared__ float ls[CC * HH];   // 64 KB
  __shared__ float lc[CC];
  const int tid = threadIdx.x;
  for (int i = tid; i < CC * HH; i += 256) ls[i] = 0.f;
  if (tid < CC) lc[tid] = 0.f;
  __syncthreads();

  const int wave = tid >> 6, lane = tid & 63;
  const int base = blockIdx.x * 1024 + wave * 256;
#pragma unroll 2
  for (int it = 0; it < 256; ++it) {
    const int n = base + it;
    const int a = assign[n];
    const float* xr = x + (size_t)n * HH;
    float v[8];
#pragma unroll
    for (int j = 0; j < 8; ++j) v[j] = xr[j * 64 + lane];
    if (lane == 0) atomicAdd(&lc[a], 1.f);
#pragma unroll
    for (int j = 0; j < 8; ++j) atomicAdd(&ls[a * HH + j * 64 + lane], v[j]);
  }
  __syncthreads();
  for (int i = tid; i < CC * HH; i += 256) atomicAdd(&gsums[i], ls[i]);
  if (tid < CC) atomicAdd(&gcounts[tid], lc[tid]);
}

// ---------------------------------------------------------------------------
// Kernel 3: EMA centroid update
// ---------------------------------------------------------------------------
__global__ void k_upd(const float* __restrict__ cent, const float* __restrict__ sums,
                      const float* __restrict__ counts, float* __restrict__ upd) {
  const int i = blockIdx.x * 256 + threadIdx.x;   // 16384
  const int c = i >> 9;
  const float cnt = counts[c];
  const float mean = sums[i] / fmaxf(cnt, 1.f);
  upd[i] = (cnt > 0.f) ? (MOMF * cent[i] + (1.f - MOMF) * mean) : cent[i];
}

// ---------------------------------------------------------------------------
// Kernel 4: k = upd@Wk + bk ; v = upd@Wv + bv   (32x512 each)
// ---------------------------------------------------------------------------
__global__ void k_kv(const float* __restrict__ upd,
                     const float* __restrict__ Wk, const float* __restrict__ bk,
                     const float* __restrict__ Wv, const float* __restrict__ bv,
                     float* __restrict__ kbuf, float* __restrict__ vbuf) {
  const int o = blockIdx.x * 256 + threadIdx.x;   // 0..32767
  const int sel = o >> 14;
  const int idx = o & 16383;
  const int c = idx >> 9, j = idx & 511;
  const float* W = sel ? Wv : Wk;
  const float* b = sel ? bv : bk;
  const float* u = upd + c * HH;
  float s = b[j];
  for (int i = 0; i < HH; ++i) s += u[i] * W[i * HH + j];
  (sel ? vbuf : kbuf)[idx] = s;
}

// ---------------------------------------------------------------------------
// Kernel 5: M[i][h*32+c] = (Wq[i,h*64+:].k[c,h,:])/8 ; sb ; P[h*32+c][o]
// ---------------------------------------------------------------------------
__global__ void k_msp(const float* __restrict__ Wq, const float* __restrict__ bq,
                      const float* __restrict__ kbuf, const float* __restrict__ vbuf,
                      const float* __restrict__ Wo,
                      float* __restrict__ M, float* __restrict__ sb,
                      float* __restrict__ P) {
  const int b = blockIdx.x, t = threadIdx.x;
  const float scale = 0.125f;   // 1/sqrt(64)
  if (b < 512) {
    const int o = b * 256 + t;      // i*256 + j
    const int i = o >> 8, j = o & 255;
    const int h = j >> 5, c = j & 31;
    const float* wq = Wq + i * HH + h * 64;
    const float* kr = kbuf + c * HH + h * 64;
    float s = 0.f;
#pragma unroll
    for (int d = 0; d < 64; ++d) s += wq[d] * kr[d];
    M[o] = s * scale;
  } else if (b < 1024) {
    const int o = (b - 512) * 256 + t;   // row*512 + col
    const int row = o >> 9, col = o & 511;
    const int h = row >> 5, c = row & 31;
    const float* vr = vbuf + c * HH + h * 64;
    const float* wo = Wo + h * 64 * HH + col;
    float s = 0.f;
#pragma unroll
    for (int d = 0; d < 64; ++d) s += vr[d] * wo[d * HH];
    P[o] = s;
  } else if (t < 256) {
    const int h = t >> 5, c = t & 31;
    const float* kr = kbuf + c * HH + h * 64;
    const float* bqp = bq + h * 64;
    float s = 0.f;
#pragma unroll
    for (int d = 0; d < 64; ++d) s += bqp[d] * kr[d];
    sb[t] = s * scale;
  }
}

// ---------------------------------------------------------------------------
// Kernel 6 (main, fused): scores = x@M + sb -> softmax(32/head) ->
// out = attn@P + bo + x -> LayerNorm -> y.   BM=64 nodes/block, 256 thr.
// LDS: attn16 u16[64][266] (34048 B) | union{ xs f32[64][33] + Ms f32[32][260] ;
//                                            Ps f32[16][516] }  -> 75776 B total
// thread map: rg=tid>>4 (rows rg*4+i), cg=tid&15 (cols 4cg+64t+jj)
// ---------------------------------------------------------------------------
__global__ __launch_bounds__(256, 2) void k_main(
    const float* __restrict__ x, const float* __restrict__ M,
    const float* __restrict__ sb, const float* __restrict__ P,
    const float* __restrict__ bo, const float* __restrict__ lnw,
    const float* __restrict__ lnb, float* __restrict__ y) {
  __shared__ __align__(16) unsigned char lds[75776];
  unsigned short* attn16 = (unsigned short*)lds;        // stride 266 ushorts
  float* xs = (float*)(lds + 34048);                    // [64][33]
  float* Ms = (float*)(lds + 42496);                    // [32][260]
  float* Ps = (float*)(lds + 34048);                    // [16][516] (phase 2)
  const int tid = threadIdx.x;
  const int rg = tid >> 4, cg = tid & 15;
  const size_t n0 = (size_t)blockIdx.x * 64;

  // ---- phase 1: scores ----
  float4 acc1[4][4];
  {
    float4 sb4[4];
#pragma unroll
    for (int t = 0; t < 4; ++t) sb4[t] = *(const float4*)&sb[4 * cg + 64 * t];
#pragma unroll
    for (int i = 0; i < 4; ++i)
#pragma unroll
      for (int t = 0; t < 4; ++t) acc1[i][t] = sb4[t];
  }

  for (int kk = 0; kk < 512; kk += 32) {
#pragma unroll
    for (int pass = 0; pass < 2; ++pass) {
      const int r = pass * 32 + (tid >> 3);
      const int c4 = (tid & 7) * 4;
      float4 v = *(const float4*)&x[(n0 + r) * HH + kk + c4];
      xs[r * 33 + c4 + 0] = v.x; xs[r * 33 + c4 + 1] = v.y;
      xs[r * 33 + c4 + 2] = v.z; xs[r * 33 + c4 + 3] = v.w;
    }
    {
      const int k = tid >> 3, c4 = (tid & 7) * 4;
#pragma unroll
      for (int t = 0; t < 8; ++t)
        *(float4*)&Ms[k * 260 + c4 + 32 * t] =
            *(const float4*)&M[(kk + k) * 256 + c4 + 32 * t];
    }
    __syncthreads();
    for (int k = 0; k < 32; ++k) {
      float a[4];
#pragma unroll
      for (int i = 0; i < 4; ++i) a[i] = xs[(rg * 4 + i) * 33 + k];
#pragma unroll
      for (int t = 0; t < 4; ++t) {
        float4 m = *(const float4*)&Ms[k * 260 + 4 * cg + 64 * t];
#pragma unroll
        for (int i = 0; i < 4; ++i) {
          acc1[i][t].x += a[i] * m.x; acc1[i][t].y += a[i] * m.y;
          acc1[i][t].z += a[i] * m.z; acc1[i][t].w += a[i] * m.w;
        }
      }
    }
    __syncthreads();
  }

  // ---- softmax over c=32 per (row, head). cols j=4cg+64t+jj:
  //      h = 2t + (cg>=8), c = 4*(cg&7)+jj -> reduce over 8-lane cg-octet.
#pragma unroll
  for (int i = 0; i < 4; ++i) {
    const int r = rg * 4 + i;
#pragma unroll
    for (int t = 0; t < 4; ++t) {
      float4 s = acc1[i][t];
      float m = fmaxf(fmaxf(s.x, s.y), fmaxf(s.z, s.w));
      m = fmaxf(m, __shfl_xor(m, 1));
      m = fmaxf(m, __shfl_xor(m, 2));
      m = fmaxf(m, __shfl_xor(m, 4));
      float4 e;
      e.x = __expf(s.x - m); e.y = __expf(s.y - m);
      e.z = __expf(s.z - m); e.w = __expf(s.w - m);
      float sum = e.x + e.y + e.z + e.w;
      sum += __shfl_xor(sum, 1);
      sum += __shfl_xor(sum, 2);
      sum += __shfl_xor(sum, 4);
      const float inv = 1.f / sum;
      // pack to bf16, store as 2 dwords (4-byte aligned at stride 266)
      unsigned int lo = (unsigned int)f2bf(e.x * inv) | ((unsigned int)f2bf(e.y * inv) << 16);
      unsigned int hi = (unsigned int)f2bf(e.z * inv) | ((unsigned int)f2bf(e.w * inv) << 16);
      unsigned int* p = (unsigned int*)&attn16[r * 266 + 4 * cg + 64 * t];
      p[0] = lo; p[1] = hi;
    }
  }
  __syncthreads();

  // ---- phase 2: out = attn @ P ----
  float4 acc2[4][8];
#pragma unroll
  for (int i = 0; i < 4; ++i)
#pragma unroll
    for (int t = 0; t < 8; ++t) acc2[i][t] = make_float4(0.f, 0.f, 0.f, 0.f);

  for (int kk = 0; kk < 256; kk += 16) {
#pragma unroll
    for (int pass = 0; pass < 2; ++pass) {
      const int k = pass * 8 + (tid >> 5);
      const int c4 = (tid & 31) * 4;
#pragma unroll
      for (int t = 0; t < 4; ++t)
        *(float4*)&Ps[k * 516 + c4 + 128 * t] =
            *(const float4*)&P[(kk + k) * 512 + c4 + 128 * t];
    }
    __syncthreads();
    for (int k = 0; k < 16; ++k) {
      float a[4];
#pragma unroll
      for (int i = 0; i < 4; ++i)
        a[i] = bf2f(attn16[(rg * 4 + i) * 266 + kk + k]);
#pragma unroll
      for (int t = 0; t < 8; ++t) {
        float4 p = *(const float4*)&Ps[k * 516 + 4 * cg + 64 * t];
#pragma unroll
        for (int i = 0; i < 4; ++i) {
          acc2[i][t].x += a[i] * p.x; acc2[i][t].y += a[i] * p.y;
          acc2[i][t].z += a[i] * p.z; acc2[i][t].w += a[i] * p.w;
        }
      }
    }
    __syncthreads();
  }

  // ---- epilogue: + bo + residual, LayerNorm, store ----
#pragma unroll
  for (int t = 0; t < 8; ++t) {
    float4 b = *(const float4*)&bo[4 * cg + 64 * t];
#pragma unroll
    for (int i = 0; i < 4; ++i) {
      acc2[i][t].x += b.x; acc2[i][t].y += b.y;
      acc2[i][t].z += b.z; acc2[i][t].w += b.w;
    }
  }
#pragma unroll
  for (int i = 0; i < 4; ++i) {
    const size_t r = n0 + rg * 4 + i;
#pragma unroll
    for (int t = 0; t < 8; ++t) {
      float4 xv = *(const float4*)&x[r * HH + 4 * cg + 64 * t];
      acc2[i][t].x += xv.x; acc2[i][t].y += xv.y;
      acc2[i][t].z += xv.z; acc2[i][t].w += xv.w;
    }
    float s1 = 0.f, s2 = 0.f;
#pragma unroll
    for (int t = 0; t < 8; ++t) {
      float4 v = acc2[i][t];
      s1 += v.x + v.y + v.z + v.w;
      s2 += v.x * v.x + v.y * v.y + v.z * v.z + v.w * v.w;
    }
    s1 += __shfl_xor(s1, 1); s2 += __shfl_xor(s2, 1);
    s1 += __shfl_xor(s1, 2); s2 += __shfl_xor(s2, 2);
    s1 += __shfl_xor(s1, 4); s2 += __shfl_xor(s2, 4);
    s1 += __shfl_xor(s1, 8); s2 += __shfl_xor(s2, 8);
    const float mean = s1 * (1.f / 512.f);
    const float var = s2 * (1.f / 512.f) - mean * mean;
    const float rstd = rsqrtf(var + 1e-5f);
#pragma unroll
    for (int t = 0; t < 8; ++t) {
      float4 w = *(const float4*)&lnw[4 * cg + 64 * t];
      float4 bb = *(const float4*)&lnb[4 * cg + 64 * t];
      float4 v = acc2[i][t];
      float4 o;
      o.x = (v.x - mean) * rstd * w.x + bb.x;
      o.y = (v.y - mean) * rstd * w.y + bb.y;
      o.z = (v.z - mean) * rstd * w.z + bb.z;
      o.w = (v.w - mean) * rstd * w.w + bb.w;
      *(float4*)&y[r * HH + 4 * cg + 64 * t] = o;
    }
  }
}

// ---------------------------------------------------------------------------
extern "C" void kernel_launch(void* const* d_in, const int* in_sizes, int n_in,
                              void* d_out, int out_size, void* d_ws, size_t ws_size,
                              hipStream_t stream) {
  const float* x    = (const float*)d_in[0];
  const float* cent = (const float*)d_in[1];
  const float* Wq   = (const float*)d_in[2];
  const float* bq   = (const float*)d_in[3];
  const float* Wk   = (const float*)d_in[4];
  const float* bk   = (const float*)d_in[5];
  const float* Wv   = (const float*)d_in[6];
  const float* bv   = (const float*)d_in[7];
  const float* Wo   = (const float*)d_in[8];
  const float* bo   = (const float*)d_in[9];
  const float* lnw  = (const float*)d_in[10];
  const float* lnb  = (const float*)d_in[11];
  float* ws = (float*)d_ws;
  float* y  = (float*)d_out;

  hipMemsetAsync(ws, 0, (16384 + 32) * sizeof(float), stream);
  k_assign<<<512, 512, 0, stream>>>(x, cent, (int*)(ws + WS_ASSIGN));
  k_sums<<<256, 256, 0, stream>>>(x, (const int*)(ws + WS_ASSIGN),
                                  ws + WS_SUMS, ws + WS_COUNTS);
  k_upd<<<64, 256, 0, stream>>>(cent, ws + WS_SUMS, ws + WS_COUNTS, ws + WS_UPD);
  k_kv<<<128, 256, 0, stream>>>(ws + WS_UPD, Wk, bk, Wv, bv,
                                ws + WS_KBUF, ws + WS_VBUF);
  k_msp<<<1025, 256, 0, stream>>>(Wq, bq, ws + WS_KBUF, ws + WS_VBUF, Wo,
                                  ws + WS_M, ws + WS_SB, ws + WS_P);
  k_main<<<4096, 256, 0, stream>>>(x, ws + WS_M, ws + WS_SB, ws + WS_P,
                                   bo, lnw, lnb, y);
}

// Round 2
// 2260.002 us; speedup vs baseline: 1.1709x; 1.1709x over previous
//
#include <hip/hip_runtime.h>

#define NN 262144
#define HH 512
#define CC 32
#define MOMF 0.99f

// ws layout (float offsets)
#define WS_SUMS   0
#define WS_COUNTS 16384
#define WS_UPD    16416
#define WS_KBUF   32800
#define WS_VBUF   49184
#define WS_SB     65568
#define WS_MT     65824    // ushort[256*512] (bf16)  = 65536 floats-worth
#define WS_PT     131360   // ushort[512*256] (bf16)
#define WS_ASSIGN 196896   // int[262144]

typedef __attribute__((ext_vector_type(8))) short s8v;
typedef __attribute__((ext_vector_type(4))) float f4v;
typedef __attribute__((ext_vector_type(4))) unsigned int u4v;

static __device__ __forceinline__ unsigned short f2bf(float f) {
  unsigned int u = __float_as_uint(f);
  u += 0x7FFFu + ((u >> 16) & 1u);   // round-to-nearest-even
  return (unsigned short)(u >> 16);
}
static __device__ __forceinline__ unsigned int pk2bf(float a, float b) {
  return (unsigned int)f2bf(a) | ((unsigned int)f2bf(b) << 16);
}

// ---------------------------------------------------------------------------
// Kernel 1: nearest-centroid assignment. argmin_c(||c||^2 - 2 x.c)
// ---------------------------------------------------------------------------
__global__ __launch_bounds__(512) void k_assign(const float* __restrict__ x,
                                                const float* __restrict__ cent,
                                                int* __restrict__ assign) {
  __shared__ __align__(16) float cl[CC * HH];   // 64 KB
  __shared__ float cn[CC];
  __shared__ float scratch[512];
  const int tid = threadIdx.x;

  for (int i = tid * 4; i < CC * HH; i += 512 * 4)
    *(float4*)&cl[i] = *(const float4*)&cent[i];
  __syncthreads();

  {
    int c = tid >> 4, kk = tid & 15;
    float p = 0.f;
    for (int m = 0; m < 32; ++m) { float v = cl[c * HH + kk + 16 * m]; p += v * v; }
    scratch[tid] = p;
  }
  __syncthreads();
  if (tid < CC) {
    float s = 0.f;
    for (int m = 0; m < 16; ++m) s += scratch[tid * 16 + m];
    cn[tid] = s;
  }
  __syncthreads();

  const int n = blockIdx.x * 512 + tid;
  float acc[CC];
#pragma unroll
  for (int c = 0; c < CC; ++c) acc[c] = 0.f;
  const float* xr = x + (size_t)n * HH;
  for (int kk = 0; kk < HH; kk += 8) {
    float4 a0 = *(const float4*)&xr[kk];
    float4 a1 = *(const float4*)&xr[kk + 4];
#pragma unroll
    for (int c = 0; c < CC; ++c) {
      float4 c0 = *(const float4*)&cl[c * HH + kk];
      float4 c1 = *(const float4*)&cl[c * HH + kk + 4];
      acc[c] += a0.x * c0.x + a0.y * c0.y + a0.z * c0.z + a0.w * c0.w
              + a1.x * c1.x + a1.y * c1.y + a1.z * c1.z + a1.w * c1.w;
    }
  }
  float best = 3.4e38f; int bi = 0;
#pragma unroll
  for (int c = 0; c < CC; ++c) {
    float s = cn[c] - 2.f * acc[c];
    if (s < best) { best = s; bi = c; }
  }
  assign[n] = bi;
}

// ---------------------------------------------------------------------------
// Kernel 2: segment sums + counts (wave-per-node, LDS accumulate)
// ---------------------------------------------------------------------------
__global__ __launch_bounds__(256) void k_sums(const float* __restrict__ x,
                                              const int* __restrict__ assign,
                                              float* __restrict__ gsums,
                                              float* __restrict__ gcounts) {
  __shared__ float ls[CC * HH];   // 64 KB
  __shared__ float lc[CC];
  const int tid = threadIdx.x;
  for (int i = tid; i < CC * HH; i += 256) ls[i] = 0.f;
  if (tid < CC) lc[tid] = 0.f;
  __syncthreads();

  const int wave = tid >> 6, lane = tid & 63;
  const int base = blockIdx.x * 1024 + wave * 256;
#pragma unroll 2
  for (int it = 0; it < 256; ++it) {
    const int n = base + it;
    const int a = assign[n];
    const float* xr = x + (size_t)n * HH;
    float v[8];
#pragma unroll
    for (int j = 0; j < 8; ++j) v[j] = xr[j * 64 + lane];
    if (lane == 0) atomicAdd(&lc[a], 1.f);
#pragma unroll
    for (int j = 0; j < 8; ++j) atomicAdd(&ls[a * HH + j * 64 + lane], v[j]);
  }
  __syncthreads();
  for (int i = tid; i < CC * HH; i += 256) atomicAdd(&gsums[i], ls[i]);
  if (tid < CC) atomicAdd(&gcounts[tid], lc[tid]);
}

// ---------------------------------------------------------------------------
// Kernel 3: EMA centroid update
// ---------------------------------------------------------------------------
__global__ void k_upd(const float* __restrict__ cent, const float* __restrict__ sums,
                      const float* __restrict__ counts, float* __restrict__ upd) {
  const int i = blockIdx.x * 256 + threadIdx.x;   // 16384
  const int c = i >> 9;
  const float cnt = counts[c];
  const float mean = sums[i] / fmaxf(cnt, 1.f);
  upd[i] = (cnt > 0.f) ? (MOMF * cent[i] + (1.f - MOMF) * mean) : cent[i];
}

// ---------------------------------------------------------------------------
// Kernel 4: k = upd@Wk + bk ; v = upd@Wv + bv   (32x512 each)
// ---------------------------------------------------------------------------
__global__ void k_kv(const float* __restrict__ upd,
                     const float* __restrict__ Wk, const float* __restrict__ bk,
                     const float* __restrict__ Wv, const float* __restrict__ bv,
                     float* __restrict__ kbuf, float* __restrict__ vbuf) {
  const int o = blockIdx.x * 256 + threadIdx.x;   // 0..32767
  const int sel = o >> 14;
  const int idx = o & 16383;
  const int c = idx >> 9, j = idx & 511;
  const float* W = sel ? Wv : Wk;
  const float* b = sel ? bv : bk;
  const float* u = upd + c * HH;
  float s = b[j];
  for (int i = 0; i < HH; ++i) s += u[i] * W[i * HH + j];
  (sel ? vbuf : kbuf)[idx] = s;
}

// ---------------------------------------------------------------------------
// Kernel 5: Mt[hc][i] = (Wq[i,h*64+:].k[c,h,:])/8 (bf16, transposed);
//           sb[hc]; Pt[o][hc] = v[c,h,:].Wo[h*64+:,o] + bo[o]/8 (bf16)
// ---------------------------------------------------------------------------
__global__ void k_msp(const float* __restrict__ Wq, const float* __restrict__ bq,
                      const float* __restrict__ kbuf, const float* __restrict__ vbuf,
                      const float* __restrict__ Wo, const float* __restrict__ bo,
                      unsigned short* __restrict__ Mt, float* __restrict__ sb,
                      unsigned short* __restrict__ Pt) {
  const int b = blockIdx.x, t = threadIdx.x;
  const float scale = 0.125f;   // 1/sqrt(64)
  if (b < 512) {
    const int o = b * 256 + t;          // hc*512 + i
    const int hc = o >> 9, i = o & 511;
    const int h = hc >> 5, c = hc & 31;
    const float* wq = Wq + i * HH + h * 64;
    const float* kr = kbuf + c * HH + h * 64;
    float s = 0.f;
#pragma unroll
    for (int d = 0; d < 64; ++d) s += wq[d] * kr[d];
    Mt[o] = f2bf(s * scale);
  } else if (b < 1024) {
    const int o = b - 512;              // output col (0..511)
    const int hc = t;                   // 0..255
    const int h = hc >> 5, c = hc & 31;
    const float* vr = vbuf + c * HH + h * 64;
    const float* wo = Wo + h * 64 * HH + o;
    float s = 0.f;
#pragma unroll
    for (int d = 0; d < 64; ++d) s += vr[d] * wo[d * HH];
    Pt[o * 256 + hc] = f2bf(s + bo[o] * scale);
  } else if (t < 256) {
    const int h = t >> 5, c = t & 31;
    const float* kr = kbuf + c * HH + h * 64;
    const float* bqp = bq + h * 64;
    float s = 0.f;
#pragma unroll
    for (int d = 0; d < 64; ++d) s += bqp[d] * kr[d];
    sb[t] = s * scale;
  }
}

// ---------------------------------------------------------------------------
// Kernel 6 (main, MFMA): S^T = Mt x^T -> softmax -> C2^T = Pt attn^T
// -> +residual -> LayerNorm -> y.  BM=64 rows/block, 4 waves (16 rows each).
// All transposed so A-frags read 16B contiguous from Mt/Pt (L2-hot, no LDS).
// ---------------------------------------------------------------------------
__global__ __launch_bounds__(256, 2) void k_main(
    const float* __restrict__ x, const unsigned short* __restrict__ Mt,
    const float* __restrict__ sb, const unsigned short* __restrict__ Pt,
    const float* __restrict__ lnw, const float* __restrict__ lnb,
    float* __restrict__ y) {
  const int tid = threadIdx.x;
  const int w = tid >> 6, l = tid & 63;
  const int l16 = l & 15, g = l >> 4;            // lane column / k-group
  const size_t xrow = (size_t)blockIdx.x * 64 + w * 16 + l16;
  const float* xr = x + xrow * HH;

  // ---- phase 1: S^T[score_col=16tc+4g+r][xrow] ----
  f4v acc1[16];
#pragma unroll
  for (int tc = 0; tc < 16; ++tc)
    acc1[tc] = *(const f4v*)&sb[tc * 16 + 4 * g];

  for (int kk = 0; kk < 16; ++kk) {
    // B-frag: x[xrow][32kk + 8g .. +7] fp32 -> bf16
    float4 xa = *(const float4*)&xr[kk * 32 + g * 8];
    float4 xb = *(const float4*)&xr[kk * 32 + g * 8 + 4];
    s8v bfrag;
    bfrag[0] = (short)f2bf(xa.x); bfrag[1] = (short)f2bf(xa.y);
    bfrag[2] = (short)f2bf(xa.z); bfrag[3] = (short)f2bf(xa.w);
    bfrag[4] = (short)f2bf(xb.x); bfrag[5] = (short)f2bf(xb.y);
    bfrag[6] = (short)f2bf(xb.z); bfrag[7] = (short)f2bf(xb.w);
#pragma unroll
    for (int tc = 0; tc < 16; ++tc) {
      s8v afrag = *(const s8v*)(Mt + ((size_t)(tc * 16 + l16) << 9) + kk * 32 + g * 8);
      acc1[tc] = __builtin_amdgcn_mfma_f32_16x16x32_bf16(afrag, bfrag, acc1[tc], 0, 0, 0);
    }
  }

  // ---- softmax per head h (cols 32h..32h+31): 8 in-lane + xor16/xor32 ----
  unsigned int apk[16][2];
#pragma unroll
  for (int h = 0; h < 8; ++h) {
    f4v s0 = acc1[2 * h], s1 = acc1[2 * h + 1];
    float m = fmaxf(fmaxf(fmaxf(s0[0], s0[1]), fmaxf(s0[2], s0[3])),
                    fmaxf(fmaxf(s1[0], s1[1]), fmaxf(s1[2], s1[3])));
    m = fmaxf(m, __shfl_xor(m, 16));
    m = fmaxf(m, __shfl_xor(m, 32));
    float e0 = __expf(s0[0] - m), e1 = __expf(s0[1] - m);
    float e2 = __expf(s0[2] - m), e3 = __expf(s0[3] - m);
    float e4 = __expf(s1[0] - m), e5 = __expf(s1[1] - m);
    float e6 = __expf(s1[2] - m), e7 = __expf(s1[3] - m);
    float sum = ((e0 + e1) + (e2 + e3)) + ((e4 + e5) + (e6 + e7));
    sum += __shfl_xor(sum, 16);
    sum += __shfl_xor(sum, 32);
    const float inv = 1.f / sum;
    apk[2 * h][0] = pk2bf(e0 * inv, e1 * inv);
    apk[2 * h][1] = pk2bf(e2 * inv, e3 * inv);
    apk[2 * h + 1][0] = pk2bf(e4 * inv, e5 * inv);
    apk[2 * h + 1][1] = pk2bf(e6 * inv, e7 * inv);
  }

  // ---- phase 2: C2^T[o=16to+4g+r][xrow] = sum_h Pt[o][32h..] attn^T ----
  f4v acc2[32];
#pragma unroll
  for (int to = 0; to < 32; ++to) acc2[to] = (f4v){0.f, 0.f, 0.f, 0.f};

#pragma unroll
  for (int h = 0; h < 8; ++h) {
    // build B-frag: B[k=8g+j][xrow=l16] = attn[c=32h+8g+j] via wave shuffle
    unsigned int dw[4];
#pragma unroll
    for (int d = 0; d < 4; ++d) {
      const int gsrc = 2 * (g & 1) + (d >> 1);
      const int src = l16 + 16 * gsrc;
      unsigned int t0 = (unsigned int)__shfl((int)apk[2 * h][d & 1], src, 64);
      unsigned int t1 = (unsigned int)__shfl((int)apk[2 * h + 1][d & 1], src, 64);
      dw[d] = (g < 2) ? t0 : t1;
    }
    u4v bu; bu[0] = dw[0]; bu[1] = dw[1]; bu[2] = dw[2]; bu[3] = dw[3];
    s8v bfrag = __builtin_bit_cast(s8v, bu);
#pragma unroll
    for (int to = 0; to < 32; ++to) {
      s8v afrag = *(const s8v*)(Pt + ((size_t)(to * 16 + l16) << 8) + h * 32 + g * 8);
      acc2[to] = __builtin_amdgcn_mfma_f32_16x16x32_bf16(afrag, bfrag, acc2[to], 0, 0, 0);
    }
  }

  // ---- epilogue: +residual (bo already folded into Pt), LayerNorm, store ----
  float s1 = 0.f, s2 = 0.f;
#pragma unroll
  for (int to = 0; to < 32; ++to) {
    float4 xv = *(const float4*)&xr[to * 16 + 4 * g];
    acc2[to][0] += xv.x; acc2[to][1] += xv.y;
    acc2[to][2] += xv.z; acc2[to][3] += xv.w;
    s1 += (acc2[to][0] + acc2[to][1]) + (acc2[to][2] + acc2[to][3]);
    s2 += (acc2[to][0] * acc2[to][0] + acc2[to][1] * acc2[to][1]) +
          (acc2[to][2] * acc2[to][2] + acc2[to][3] * acc2[to][3]);
  }
  s1 += __shfl_xor(s1, 16); s2 += __shfl_xor(s2, 16);
  s1 += __shfl_xor(s1, 32); s2 += __shfl_xor(s2, 32);
  const float mean = s1 * (1.f / 512.f);
  const float var = s2 * (1.f / 512.f) - mean * mean;
  const float rstd = rsqrtf(var + 1e-5f);
  float* yr = y + xrow * HH;
#pragma unroll
  for (int to = 0; to < 32; ++to) {
    float4 wv = *(const float4*)&lnw[to * 16 + 4 * g];
    float4 bv = *(const float4*)&lnb[to * 16 + 4 * g];
    float4 o;
    o.x = (acc2[to][0] - mean) * rstd * wv.x + bv.x;
    o.y = (acc2[to][1] - mean) * rstd * wv.y + bv.y;
    o.z = (acc2[to][2] - mean) * rstd * wv.z + bv.z;
    o.w = (acc2[to][3] - mean) * rstd * wv.w + bv.w;
    *(float4*)&yr[to * 16 + 4 * g] = o;
  }
}

// ---------------------------------------------------------------------------
extern "C" void kernel_launch(void* const* d_in, const int* in_sizes, int n_in,
                              void* d_out, int out_size, void* d_ws, size_t ws_size,
                              hipStream_t stream) {
  const float* x    = (const float*)d_in[0];
  const float* cent = (const float*)d_in[1];
  const float* Wq   = (const float*)d_in[2];
  const float* bq   = (const float*)d_in[3];
  const float* Wk   = (const float*)d_in[4];
  const float* bk   = (const float*)d_in[5];
  const float* Wv   = (const float*)d_in[6];
  const float* bv   = (const float*)d_in[7];
  const float* Wo   = (const float*)d_in[8];
  const float* bo   = (const float*)d_in[9];
  const float* lnw  = (const float*)d_in[10];
  const float* lnb  = (const float*)d_in[11];
  float* ws = (float*)d_ws;
  float* y  = (float*)d_out;

  hipMemsetAsync(ws, 0, (16384 + 32) * sizeof(float), stream);
  k_assign<<<512, 512, 0, stream>>>(x, cent, (int*)(ws + WS_ASSIGN));
  k_sums<<<256, 256, 0, stream>>>(x, (const int*)(ws + WS_ASSIGN),
                                  ws + WS_SUMS, ws + WS_COUNTS);
  k_upd<<<64, 256, 0, stream>>>(cent, ws + WS_SUMS, ws + WS_COUNTS, ws + WS_UPD);
  k_kv<<<128, 256, 0, stream>>>(ws + WS_UPD, Wk, bk, Wv, bv,
                                ws + WS_KBUF, ws + WS_VBUF);
  k_msp<<<1025, 256, 0, stream>>>(Wq, bq, ws + WS_KBUF, ws + WS_VBUF, Wo, bo,
                                  (unsigned short*)(ws + WS_MT), ws + WS_SB,
                                  (unsigned short*)(ws + WS_PT));
  k_main<<<4096, 256, 0, stream>>>(x, (const unsigned short*)(ws + WS_MT),
                                   ws + WS_SB, (const unsigned short*)(ws + WS_PT),
                                   lnw, lnb, y);
}

// Round 5
// 2229.594 us; speedup vs baseline: 1.1869x; 1.0136x over previous
//
#include <hip/hip_runtime.h>

#define NN 262144
#define HH 512
#define CC 32
#define MOMF 0.99f

// ws layout (float offsets) — identical to the R2-proven layout (1.84 MB).
#define WS_SUMS   0
#define WS_COUNTS 16384
#define WS_UPD    16416
#define WS_KBUF   32800
#define WS_VBUF   49184
#define WS_SB     65568
#define WS_MT     65824    // ushort[256*512] (bf16)
#define WS_PT     131360   // ushort[512*256] (bf16)
#define WS_ASSIGN 196896   // int[262144]

typedef __attribute__((ext_vector_type(8))) short s8v;
typedef __attribute__((ext_vector_type(4))) float f4v;
typedef __attribute__((ext_vector_type(4))) unsigned int u4v;

static __device__ __forceinline__ unsigned short f2bf(float f) {
  unsigned int u = __float_as_uint(f);
  u += 0x7FFFu + ((u >> 16) & 1u);   // round-to-nearest-even
  return (unsigned short)(u >> 16);
}
static __device__ __forceinline__ unsigned int pk2bf(float a, float b) {
  return (unsigned int)f2bf(a) | ((unsigned int)f2bf(b) << 16);
}

// ---------------------------------------------------------------------------
// Kernel 1: nearest-centroid assignment. argmin_c(||c||^2 - 2 x.c)
// ---------------------------------------------------------------------------
__global__ __launch_bounds__(512) void k_assign(const float* __restrict__ x,
                                                const float* __restrict__ cent,
                                                int* __restrict__ assign) {
  __shared__ __align__(16) float cl[CC * HH];   // 64 KB
  __shared__ float cn[CC];
  __shared__ float scratch[512];
  const int tid = threadIdx.x;

  for (int i = tid * 4; i < CC * HH; i += 512 * 4)
    *(float4*)&cl[i] = *(const float4*)&cent[i];
  __syncthreads();

  {
    int c = tid >> 4, kk = tid & 15;
    float p = 0.f;
    for (int m = 0; m < 32; ++m) { float v = cl[c * HH + kk + 16 * m]; p += v * v; }
    scratch[tid] = p;
  }
  __syncthreads();
  if (tid < CC) {
    float s = 0.f;
    for (int m = 0; m < 16; ++m) s += scratch[tid * 16 + m];
    cn[tid] = s;
  }
  __syncthreads();

  const int n = blockIdx.x * 512 + tid;
  float acc[CC];
#pragma unroll
  for (int c = 0; c < CC; ++c) acc[c] = 0.f;
  const float* xr = x + (size_t)n * HH;
  for (int kk = 0; kk < HH; kk += 8) {
    float4 a0 = *(const float4*)&xr[kk];
    float4 a1 = *(const float4*)&xr[kk + 4];
#pragma unroll
    for (int c = 0; c < CC; ++c) {
      float4 c0 = *(const float4*)&cl[c * HH + kk];
      float4 c1 = *(const float4*)&cl[c * HH + kk + 4];
      acc[c] += a0.x * c0.x + a0.y * c0.y + a0.z * c0.z + a0.w * c0.w
              + a1.x * c1.x + a1.y * c1.y + a1.z * c1.z + a1.w * c1.w;
    }
  }
  float best = 3.4e38f; int bi = 0;
#pragma unroll
  for (int c = 0; c < CC; ++c) {
    float s = cn[c] - 2.f * acc[c];
    if (s < best) { best = s; bi = c; }
  }
  assign[n] = bi;
}

// ---------------------------------------------------------------------------
// Kernel 2: segment sums + counts (wave-per-node, LDS accumulate) — R2 exact
// ---------------------------------------------------------------------------
__global__ __launch_bounds__(256) void k_sums(const float* __restrict__ x,
                                              const int* __restrict__ assign,
                                              float* __restrict__ gsums,
                                              float* __restrict__ gcounts) {
  __shared__ float ls[CC * HH];   // 64 KB
  __shared__ float lc[CC];
  const int tid = threadIdx.x;
  for (int i = tid; i < CC * HH; i += 256) ls[i] = 0.f;
  if (tid < CC) lc[tid] = 0.f;
  __syncthreads();

  const int wave = tid >> 6, lane = tid & 63;
  const int base = blockIdx.x * 1024 + wave * 256;
#pragma unroll 2
  for (int it = 0; it < 256; ++it) {
    const int n = base + it;
    const int a = assign[n];
    const float* xr = x + (size_t)n * HH;
    float v[8];
#pragma unroll
    for (int j = 0; j < 8; ++j) v[j] = xr[j * 64 + lane];
    if (lane == 0) atomicAdd(&lc[a], 1.f);
#pragma unroll
    for (int j = 0; j < 8; ++j) atomicAdd(&ls[a * HH + j * 64 + lane], v[j]);
  }
  __syncthreads();
  for (int i = tid; i < CC * HH; i += 256) atomicAdd(&gsums[i], ls[i]);
  if (tid < CC) atomicAdd(&gcounts[tid], lc[tid]);
}

// ---------------------------------------------------------------------------
// Kernel 3: EMA centroid update — R2 exact
// ---------------------------------------------------------------------------
__global__ void k_upd(const float* __restrict__ cent, const float* __restrict__ sums,
                      const float* __restrict__ counts, float* __restrict__ upd) {
  const int i = blockIdx.x * 256 + threadIdx.x;   // 16384
  const int c = i >> 9;
  const float cnt = counts[c];
  const float mean = sums[i] / fmaxf(cnt, 1.f);
  upd[i] = (cnt > 0.f) ? (MOMF * cent[i] + (1.f - MOMF) * mean) : cent[i];
}

// ---------------------------------------------------------------------------
// Kernel 4: k = upd@Wk + bk ; v = upd@Wv + bv   (32x512 each) — R2 exact
// ---------------------------------------------------------------------------
__global__ void k_kv(const float* __restrict__ upd,
                     const float* __restrict__ Wk, const float* __restrict__ bk,
                     const float* __restrict__ Wv, const float* __restrict__ bv,
                     float* __restrict__ kbuf, float* __restrict__ vbuf) {
  const int o = blockIdx.x * 256 + threadIdx.x;   // 0..32767
  const int sel = o >> 14;
  const int idx = o & 16383;
  const int c = idx >> 9, j = idx & 511;
  const float* W = sel ? Wv : Wk;
  const float* b = sel ? bv : bk;
  const float* u = upd + c * HH;
  float s = b[j];
  for (int i = 0; i < HH; ++i) s += u[i] * W[i * HH + j];
  (sel ? vbuf : kbuf)[idx] = s;
}

// ---------------------------------------------------------------------------
// Kernel 5: Mt (bf16, row-major transposed), sb, Pt (bf16, +bo/8) — R2 exact
// ---------------------------------------------------------------------------
__global__ void k_msp(const float* __restrict__ Wq, const float* __restrict__ bq,
                      const float* __restrict__ kbuf, const float* __restrict__ vbuf,
                      const float* __restrict__ Wo, const float* __restrict__ bo,
                      unsigned short* __restrict__ Mt, float* __restrict__ sb,
                      unsigned short* __restrict__ Pt) {
  const int b = blockIdx.x, t = threadIdx.x;
  const float scale = 0.125f;   // 1/sqrt(64)
  if (b < 512) {
    const int o = b * 256 + t;          // hc*512 + i
    const int hc = o >> 9, i = o & 511;
    const int h = hc >> 5, c = hc & 31;
    const float* wq = Wq + i * HH + h * 64;
    const float* kr = kbuf + c * HH + h * 64;
    float s = 0.f;
#pragma unroll
    for (int d = 0; d < 64; ++d) s += wq[d] * kr[d];
    Mt[o] = f2bf(s * scale);
  } else if (b < 1024) {
    const int o = b - 512;              // output col (0..511)
    const int hc = t;                   // 0..255
    const int h = hc >> 5, c = hc & 31;
    const float* vr = vbuf + c * HH + h * 64;
    const float* wo = Wo + h * 64 * HH + o;
    float s = 0.f;
#pragma unroll
    for (int d = 0; d < 64; ++d) s += vr[d] * wo[d * HH];
    Pt[o * 256 + hc] = f2bf(s + bo[o] * scale);
  } else if (t < 256) {
    const int h = t >> 5, c = t & 31;
    const float* kr = kbuf + c * HH + h * 64;
    const float* bqp = bq + h * 64;
    float s = 0.f;
#pragma unroll
    for (int d = 0; d < 64; ++d) s += bqp[d] * kr[d];
    sb[t] = s * scale;
  }
}

// ---------------------------------------------------------------------------
// Kernel 6 (main, MFMA): phases 1-2 + softmax are the R2-PROVEN code, verbatim.
// Only change: epilogue applies LN in registers (bit-identical to R2), then
// stores y through a [16][520] LDS window (4 row-windows) so every global
// store instruction covers a contiguous 2 KB run -> no write amplification.
// ---------------------------------------------------------------------------
__global__ __launch_bounds__(256, 2) void k_main(
    const float* __restrict__ x, const unsigned short* __restrict__ Mt,
    const float* __restrict__ sb, const unsigned short* __restrict__ Pt,
    const float* __restrict__ lnw, const float* __restrict__ lnb,
    float* __restrict__ y) {
  __shared__ __align__(16) float yb[16 * 520];   // 33280 B store window
  const int tid = threadIdx.x;
  const int w = tid >> 6, l = tid & 63;
  const int l16 = l & 15, g = l >> 4;            // lane column / k-group
  const size_t n0 = (size_t)blockIdx.x * 64;
  const size_t xrow = n0 + w * 16 + l16;
  const float* xr = x + xrow * HH;

  // ---- phase 1: S^T[score_col=16tc+4g+r][xrow] ----
  f4v acc1[16];
#pragma unroll
  for (int tc = 0; tc < 16; ++tc)
    acc1[tc] = *(const f4v*)&sb[tc * 16 + 4 * g];

  for (int kk = 0; kk < 16; ++kk) {
    // B-frag: x[xrow][32kk + 8g .. +7] fp32 -> bf16
    float4 xa = *(const float4*)&xr[kk * 32 + g * 8];
    float4 xb = *(const float4*)&xr[kk * 32 + g * 8 + 4];
    s8v bfrag;
    bfrag[0] = (short)f2bf(xa.x); bfrag[1] = (short)f2bf(xa.y);
    bfrag[2] = (short)f2bf(xa.z); bfrag[3] = (short)f2bf(xa.w);
    bfrag[4] = (short)f2bf(xb.x); bfrag[5] = (short)f2bf(xb.y);
    bfrag[6] = (short)f2bf(xb.z); bfrag[7] = (short)f2bf(xb.w);
#pragma unroll
    for (int tc = 0; tc < 16; ++tc) {
      s8v afrag = *(const s8v*)(Mt + ((size_t)(tc * 16 + l16) << 9) + kk * 32 + g * 8);
      acc1[tc] = __builtin_amdgcn_mfma_f32_16x16x32_bf16(afrag, bfrag, acc1[tc], 0, 0, 0);
    }
  }

  // ---- softmax per head h (cols 32h..32h+31): 8 in-lane + xor16/xor32 ----
  unsigned int apk[16][2];
#pragma unroll
  for (int h = 0; h < 8; ++h) {
    f4v s0 = acc1[2 * h], s1 = acc1[2 * h + 1];
    float m = fmaxf(fmaxf(fmaxf(s0[0], s0[1]), fmaxf(s0[2], s0[3])),
                    fmaxf(fmaxf(s1[0], s1[1]), fmaxf(s1[2], s1[3])));
    m = fmaxf(m, __shfl_xor(m, 16));
    m = fmaxf(m, __shfl_xor(m, 32));
    float e0 = __expf(s0[0] - m), e1 = __expf(s0[1] - m);
    float e2 = __expf(s0[2] - m), e3 = __expf(s0[3] - m);
    float e4 = __expf(s1[0] - m), e5 = __expf(s1[1] - m);
    float e6 = __expf(s1[2] - m), e7 = __expf(s1[3] - m);
    float sum = ((e0 + e1) + (e2 + e3)) + ((e4 + e5) + (e6 + e7));
    sum += __shfl_xor(sum, 16);
    sum += __shfl_xor(sum, 32);
    const float inv = 1.f / sum;
    apk[2 * h][0] = pk2bf(e0 * inv, e1 * inv);
    apk[2 * h][1] = pk2bf(e2 * inv, e3 * inv);
    apk[2 * h + 1][0] = pk2bf(e4 * inv, e5 * inv);
    apk[2 * h + 1][1] = pk2bf(e6 * inv, e7 * inv);
  }

  // ---- phase 2: C2^T[o=16to+4g+r][xrow] = sum_h Pt[o][32h..] attn^T ----
  f4v acc2[32];
#pragma unroll
  for (int to = 0; to < 32; ++to) acc2[to] = (f4v){0.f, 0.f, 0.f, 0.f};

#pragma unroll
  for (int h = 0; h < 8; ++h) {
    // build B-frag: B[k=8g+j][xrow=l16] = attn[c=32h+8g+j] via wave shuffle
    unsigned int dw[4];
#pragma unroll
    for (int d = 0; d < 4; ++d) {
      const int gsrc = 2 * (g & 1) + (d >> 1);
      const int src = l16 + 16 * gsrc;
      unsigned int t0 = (unsigned int)__shfl((int)apk[2 * h][d & 1], src, 64);
      unsigned int t1 = (unsigned int)__shfl((int)apk[2 * h + 1][d & 1], src, 64);
      dw[d] = (g < 2) ? t0 : t1;
    }
    u4v bu; bu[0] = dw[0]; bu[1] = dw[1]; bu[2] = dw[2]; bu[3] = dw[3];
    s8v bfrag = __builtin_bit_cast(s8v, bu);
#pragma unroll
    for (int to = 0; to < 32; ++to) {
      s8v afrag = *(const s8v*)(Pt + ((size_t)(to * 16 + l16) << 8) + h * 32 + g * 8);
      acc2[to] = __builtin_amdgcn_mfma_f32_16x16x32_bf16(afrag, bfrag, acc2[to], 0, 0, 0);
    }
  }

  // ---- epilogue: +residual (bo folded into Pt), LN in registers (R2 math) --
  float s1 = 0.f, s2 = 0.f;
#pragma unroll
  for (int to = 0; to < 32; ++to) {
    float4 xv = *(const float4*)&xr[to * 16 + 4 * g];
    acc2[to][0] += xv.x; acc2[to][1] += xv.y;
    acc2[to][2] += xv.z; acc2[to][3] += xv.w;
    s1 += (acc2[to][0] + acc2[to][1]) + (acc2[to][2] + acc2[to][3]);
    s2 += (acc2[to][0] * acc2[to][0] + acc2[to][1] * acc2[to][1]) +
          (acc2[to][2] * acc2[to][2] + acc2[to][3] * acc2[to][3]);
  }
  s1 += __shfl_xor(s1, 16); s2 += __shfl_xor(s2, 16);
  s1 += __shfl_xor(s1, 32); s2 += __shfl_xor(s2, 32);
  const float mean = s1 * (1.f / 512.f);
  const float var = s2 * (1.f / 512.f) - mean * mean;
  const float rstd = rsqrtf(var + 1e-5f);
#pragma unroll
  for (int to = 0; to < 32; ++to) {
    float4 wv = *(const float4*)&lnw[to * 16 + 4 * g];
    float4 bv = *(const float4*)&lnb[to * 16 + 4 * g];
    acc2[to][0] = (acc2[to][0] - mean) * rstd * wv.x + bv.x;
    acc2[to][1] = (acc2[to][1] - mean) * rstd * wv.y + bv.y;
    acc2[to][2] = (acc2[to][2] - mean) * rstd * wv.z + bv.z;
    acc2[to][3] = (acc2[to][3] - mean) * rstd * wv.w + bv.w;
  }

  // ---- store via LDS windows: wave j dumps its 16 rows; all threads store
  //      contiguous 2 KB runs (no write amplification) ----
  const int prow = tid >> 7;               // 0..1
  const int pc = (tid & 127) * 4;          // float col within row
  for (int j = 0; j < 4; ++j) {
    __syncthreads();                       // window free (prev stores done)
    if (w == j) {
#pragma unroll
      for (int to = 0; to < 32; ++to)
        *(f4v*)&yb[l16 * 520 + to * 16 + 4 * g] = acc2[to];
    }
    __syncthreads();                       // publish
#pragma unroll
    for (int p = 0; p < 8; ++p)
      *(float4*)&y[(n0 + j * 16 + p * 2 + prow) * HH + pc] =
          *(const float4*)&yb[(p * 2 + prow) * 520 + pc];
  }
}

// ---------------------------------------------------------------------------
extern "C" void kernel_launch(void* const* d_in, const int* in_sizes, int n_in,
                              void* d_out, int out_size, void* d_ws, size_t ws_size,
                              hipStream_t stream) {
  const float* x    = (const float*)d_in[0];
  const float* cent = (const float*)d_in[1];
  const float* Wq   = (const float*)d_in[2];
  const float* bq   = (const float*)d_in[3];
  const float* Wk   = (const float*)d_in[4];
  const float* bk   = (const float*)d_in[5];
  const float* Wv   = (const float*)d_in[6];
  const float* bv   = (const float*)d_in[7];
  const float* Wo   = (const float*)d_in[8];
  const float* bo   = (const float*)d_in[9];
  const float* lnw  = (const float*)d_in[10];
  const float* lnb  = (const float*)d_in[11];
  float* ws = (float*)d_ws;
  float* y  = (float*)d_out;

  hipMemsetAsync(ws, 0, (16384 + 32) * sizeof(float), stream);
  k_assign<<<512, 512, 0, stream>>>(x, cent, (int*)(ws + WS_ASSIGN));
  k_sums<<<256, 256, 0, stream>>>(x, (const int*)(ws + WS_ASSIGN),
                                  ws + WS_SUMS, ws + WS_COUNTS);
  k_upd<<<64, 256, 0, stream>>>(cent, ws + WS_SUMS, ws + WS_COUNTS, ws + WS_UPD);
  k_kv<<<128, 256, 0, stream>>>(ws + WS_UPD, Wk, bk, Wv, bv,
                                ws + WS_KBUF, ws + WS_VBUF);
  k_msp<<<1025, 256, 0, stream>>>(Wq, bq, ws + WS_KBUF, ws + WS_VBUF, Wo, bo,
                                  (unsigned short*)(ws + WS_MT), ws + WS_SB,
                                  (unsigned short*)(ws + WS_PT));
  k_main<<<4096, 256, 0, stream>>>(x, (const unsigned short*)(ws + WS_MT),
                                   ws + WS_SB, (const unsigned short*)(ws + WS_PT),
                                   lnw, lnb, y);
}

// Round 6
// 1513.095 us; speedup vs baseline: 1.7489x; 1.4735x over previous
//
#include <hip/hip_runtime.h>

#define NN 262144
#define HH 512
#define CC 32
#define MOMF 0.99f

// ws layout (float offsets) — R2/R5-proven region sizes.
#define WS_SUMS   0
#define WS_COUNTS 16384
#define WS_UPD    16416
#define WS_KBUF   32800
#define WS_VBUF   49184
#define WS_SB     65568
#define WS_MT     65824    // ushort[256*512] (bf16)
#define WS_PT     131360   // ushort[512*256] (bf16)

typedef __attribute__((ext_vector_type(8))) short s8v;
typedef __attribute__((ext_vector_type(4))) float f4v;
typedef __attribute__((ext_vector_type(4))) unsigned int u4v;

static __device__ __forceinline__ unsigned short f2bf(float f) {
  unsigned int u = __float_as_uint(f);
  u += 0x7FFFu + ((u >> 16) & 1u);   // round-to-nearest-even
  return (unsigned short)(u >> 16);
}
static __device__ __forceinline__ unsigned int pk2bf(float a, float b) {
  return (unsigned int)f2bf(a) | ((unsigned int)f2bf(b) << 16);
}

// ---------------------------------------------------------------------------
// Kernel 1 (fused k-means step): phase A = R5 k_assign body (argmin -> LDS),
// phase B = R5 k_sums body (wave-parallel accumulate) reading LDS assign.
// The 64KB centroid buffer is reused as the accumulator after a barrier.
// ---------------------------------------------------------------------------
__global__ __launch_bounds__(512) void k_km(const float* __restrict__ x,
                                            const float* __restrict__ cent,
                                            float* __restrict__ gsums,
                                            float* __restrict__ gcounts) {
  __shared__ __align__(16) float buf[CC * HH];   // cl (phase A) / ls (phase B)
  __shared__ float cn[CC];
  __shared__ float scratch[512];
  __shared__ float lc[CC];
  __shared__ unsigned char sa[512];
  const int tid = threadIdx.x;

  for (int i = tid * 4; i < CC * HH; i += 512 * 4)
    *(float4*)&buf[i] = *(const float4*)&cent[i];
  __syncthreads();

  {
    int c = tid >> 4, kk = tid & 15;
    float p = 0.f;
    for (int m = 0; m < 32; ++m) { float v = buf[c * HH + kk + 16 * m]; p += v * v; }
    scratch[tid] = p;
  }
  __syncthreads();
  if (tid < CC) {
    float s = 0.f;
    for (int m = 0; m < 16; ++m) s += scratch[tid * 16 + m];
    cn[tid] = s;
  }
  __syncthreads();

  const int n = blockIdx.x * 512 + tid;
  {
    float acc[CC];
#pragma unroll
    for (int c = 0; c < CC; ++c) acc[c] = 0.f;
    const float* xr = x + (size_t)n * HH;
    for (int kk = 0; kk < HH; kk += 8) {
      float4 a0 = *(const float4*)&xr[kk];
      float4 a1 = *(const float4*)&xr[kk + 4];
#pragma unroll
      for (int c = 0; c < CC; ++c) {
        float4 c0 = *(const float4*)&buf[c * HH + kk];
        float4 c1 = *(const float4*)&buf[c * HH + kk + 4];
        acc[c] += a0.x * c0.x + a0.y * c0.y + a0.z * c0.z + a0.w * c0.w
                + a1.x * c1.x + a1.y * c1.y + a1.z * c1.z + a1.w * c1.w;
      }
    }
    float best = 3.4e38f; int bi = 0;
#pragma unroll
    for (int c = 0; c < CC; ++c) {
      float s = cn[c] - 2.f * acc[c];
      if (s < best) { best = s; bi = c; }
    }
    sa[tid] = (unsigned char)bi;
  }
  __syncthreads();                     // all centroid reads done

  // phase B: reuse buf as ls
  for (int i = tid; i < CC * HH; i += 512) buf[i] = 0.f;
  if (tid < CC) lc[tid] = 0.f;
  __syncthreads();

  const int wave = tid >> 6, lane = tid & 63;
  const int nb = blockIdx.x * 512 + wave * 64;
  for (int it = 0; it < 64; ++it) {
    const int a = (int)sa[wave * 64 + it];
    const float* xp = x + (size_t)(nb + it) * HH;
    float v[8];
#pragma unroll
    for (int j = 0; j < 8; ++j) v[j] = xp[j * 64 + lane];
    if (lane == 0) atomicAdd(&lc[a], 1.f);
#pragma unroll
    for (int j = 0; j < 8; ++j) atomicAdd(&buf[a * HH + j * 64 + lane], v[j]);
  }
  __syncthreads();
  for (int i = tid; i < CC * HH; i += 512) atomicAdd(&gsums[i], buf[i]);
  if (tid < CC) atomicAdd(&gcounts[tid], lc[tid]);
}

// ---------------------------------------------------------------------------
// Kernel 3: EMA centroid update — R2 exact
// ---------------------------------------------------------------------------
__global__ void k_upd(const float* __restrict__ cent, const float* __restrict__ sums,
                      const float* __restrict__ counts, float* __restrict__ upd) {
  const int i = blockIdx.x * 256 + threadIdx.x;   // 16384
  const int c = i >> 9;
  const float cnt = counts[c];
  const float mean = sums[i] / fmaxf(cnt, 1.f);
  upd[i] = (cnt > 0.f) ? (MOMF * cent[i] + (1.f - MOMF) * mean) : cent[i];
}

// ---------------------------------------------------------------------------
// Kernel 4: k = upd@Wk + bk ; v = upd@Wv + bv   (32x512 each) — R2 exact
// ---------------------------------------------------------------------------
__global__ void k_kv(const float* __restrict__ upd,
                     const float* __restrict__ Wk, const float* __restrict__ bk,
                     const float* __restrict__ Wv, const float* __restrict__ bv,
                     float* __restrict__ kbuf, float* __restrict__ vbuf) {
  const int o = blockIdx.x * 256 + threadIdx.x;   // 0..32767
  const int sel = o >> 14;
  const int idx = o & 16383;
  const int c = idx >> 9, j = idx & 511;
  const float* W = sel ? Wv : Wk;
  const float* b = sel ? bv : bk;
  const float* u = upd + c * HH;
  float s = b[j];
  for (int i = 0; i < HH; ++i) s += u[i] * W[i * HH + j];
  (sel ? vbuf : kbuf)[idx] = s;
}

// ---------------------------------------------------------------------------
// Kernel 5: Mt (bf16, row-major transposed), sb, Pt (bf16, +bo/8) — R2 exact
// ---------------------------------------------------------------------------
__global__ void k_msp(const float* __restrict__ Wq, const float* __restrict__ bq,
                      const float* __restrict__ kbuf, const float* __restrict__ vbuf,
                      const float* __restrict__ Wo, const float* __restrict__ bo,
                      unsigned short* __restrict__ Mt, float* __restrict__ sb,
                      unsigned short* __restrict__ Pt) {
  const int b = blockIdx.x, t = threadIdx.x;
  const float scale = 0.125f;   // 1/sqrt(64)
  if (b < 512) {
    const int o = b * 256 + t;          // hc*512 + i
    const int hc = o >> 9, i = o & 511;
    const int h = hc >> 5, c = hc & 31;
    const float* wq = Wq + i * HH + h * 64;
    const float* kr = kbuf + c * HH + h * 64;
    float s = 0.f;
#pragma unroll
    for (int d = 0; d < 64; ++d) s += wq[d] * kr[d];
    Mt[o] = f2bf(s * scale);
  } else if (b < 1024) {
    const int o = b - 512;              // output col (0..511)
    const int hc = t;                   // 0..255
    const int h = hc >> 5, c = hc & 31;
    const float* vr = vbuf + c * HH + h * 64;
    const float* wo = Wo + h * 64 * HH + o;
    float s = 0.f;
#pragma unroll
    for (int d = 0; d < 64; ++d) s += vr[d] * wo[d * HH];
    Pt[o * 256 + hc] = f2bf(s + bo[o] * scale);
  } else if (t < 256) {
    const int h = t >> 5, c = t & 31;
    const float* kr = kbuf + c * HH + h * 64;
    const float* bqp = bq + h * 64;
    float s = 0.f;
#pragma unroll
    for (int d = 0; d < 64; ++d) s += bqp[d] * kr[d];
    sb[t] = s * scale;
  }
}

// ---------------------------------------------------------------------------
// Kernel 6 (main, MFMA): R5-verbatim dataflow; ONLY change is that A-frags now
// come from LDS-staged slices (Mt kk-slice 16KB per k-step, Pt h-slice 32KB
// per head), cooperatively copied once per block and reused by all 4 waves.
// 80B LDS row stride -> 16B-aligned ds_read_b128, <=2-way bank aliasing.
// ---------------------------------------------------------------------------
__global__ __launch_bounds__(256, 2) void k_main(
    const float* __restrict__ x, const unsigned short* __restrict__ Mt,
    const float* __restrict__ sb, const unsigned short* __restrict__ Pt,
    const float* __restrict__ lnw, const float* __restrict__ lnb,
    float* __restrict__ y) {
  __shared__ __align__(16) unsigned char smem[40960];  // stage / store window
  float* yb = (float*)smem;                            // [16][520] fp32 window
  const unsigned char* Mtb = (const unsigned char*)Mt;
  const unsigned char* Ptb = (const unsigned char*)Pt;
  const int tid = threadIdx.x;
  const int w = tid >> 6, l = tid & 63;
  const int l16 = l & 15, g = l >> 4;            // lane column / k-group
  const size_t n0 = (size_t)blockIdx.x * 64;
  const size_t xrow = n0 + w * 16 + l16;
  const float* xr = x + xrow * HH;

  // ---- phase 1: S^T[score_col=16tc+4g+r][xrow] ----
  f4v acc1[16];
#pragma unroll
  for (int tc = 0; tc < 16; ++tc)
    acc1[tc] = *(const f4v*)&sb[tc * 16 + 4 * g];

  for (int kk = 0; kk < 16; ++kk) {
    // x B-frag loads (global, R5-exact)
    float4 xa = *(const float4*)&xr[kk * 32 + g * 8];
    float4 xb = *(const float4*)&xr[kk * 32 + g * 8 + 4];
    __syncthreads();                         // prev slice reads done
    // stage Mt kk-slice: row sc=tid (64B data per row at stride 80)
#pragma unroll
    for (int r = 0; r < 4; ++r)
      *(u4v*)(smem + tid * 80 + r * 16) =
          *(const u4v*)(Mtb + tid * 1024 + kk * 64 + r * 16);
    __syncthreads();                         // publish
    s8v bfrag;
    bfrag[0] = (short)f2bf(xa.x); bfrag[1] = (short)f2bf(xa.y);
    bfrag[2] = (short)f2bf(xa.z); bfrag[3] = (short)f2bf(xa.w);
    bfrag[4] = (short)f2bf(xb.x); bfrag[5] = (short)f2bf(xb.y);
    bfrag[6] = (short)f2bf(xb.z); bfrag[7] = (short)f2bf(xb.w);
#pragma unroll
    for (int tc = 0; tc < 16; ++tc) {
      s8v afrag = *(const s8v*)(smem + (tc * 16 + l16) * 80 + g * 16);
      acc1[tc] = __builtin_amdgcn_mfma_f32_16x16x32_bf16(afrag, bfrag, acc1[tc], 0, 0, 0);
    }
  }

  // ---- softmax per head h (cols 32h..32h+31): 8 in-lane + xor16/xor32 ----
  unsigned int apk[16][2];
#pragma unroll
  for (int h = 0; h < 8; ++h) {
    f4v s0 = acc1[2 * h], s1 = acc1[2 * h + 1];
    float m = fmaxf(fmaxf(fmaxf(s0[0], s0[1]), fmaxf(s0[2], s0[3])),
                    fmaxf(fmaxf(s1[0], s1[1]), fmaxf(s1[2], s1[3])));
    m = fmaxf(m, __shfl_xor(m, 16));
    m = fmaxf(m, __shfl_xor(m, 32));
    float e0 = __expf(s0[0] - m), e1 = __expf(s0[1] - m);
    float e2 = __expf(s0[2] - m), e3 = __expf(s0[3] - m);
    float e4 = __expf(s1[0] - m), e5 = __expf(s1[1] - m);
    float e6 = __expf(s1[2] - m), e7 = __expf(s1[3] - m);
    float sum = ((e0 + e1) + (e2 + e3)) + ((e4 + e5) + (e6 + e7));
    sum += __shfl_xor(sum, 16);
    sum += __shfl_xor(sum, 32);
    const float inv = 1.f / sum;
    apk[2 * h][0] = pk2bf(e0 * inv, e1 * inv);
    apk[2 * h][1] = pk2bf(e2 * inv, e3 * inv);
    apk[2 * h + 1][0] = pk2bf(e4 * inv, e5 * inv);
    apk[2 * h + 1][1] = pk2bf(e6 * inv, e7 * inv);
  }

  // ---- phase 2: C2^T[o=16to+4g+r][xrow] = sum_h Pt[o][32h..] attn^T ----
  f4v acc2[32];
#pragma unroll
  for (int to = 0; to < 32; ++to) acc2[to] = (f4v){0.f, 0.f, 0.f, 0.f};

  for (int h = 0; h < 8; ++h) {
    // B-frag from registers via wave shuffle (R5-exact)
    unsigned int dw[4];
#pragma unroll
    for (int d = 0; d < 4; ++d) {
      const int gsrc = 2 * (g & 1) + (d >> 1);
      const int src = l16 + 16 * gsrc;
      unsigned int t0 = (unsigned int)__shfl((int)apk[2 * h][d & 1], src, 64);
      unsigned int t1 = (unsigned int)__shfl((int)apk[2 * h + 1][d & 1], src, 64);
      dw[d] = (g < 2) ? t0 : t1;
    }
    u4v bu; bu[0] = dw[0]; bu[1] = dw[1]; bu[2] = dw[2]; bu[3] = dw[3];
    s8v bfrag = __builtin_bit_cast(s8v, bu);
    __syncthreads();                         // prev slice reads done
    // stage Pt h-slice: rows o=2*tid, 2*tid+1 (64B data per row at stride 80)
#pragma unroll
    for (int oo = 0; oo < 2; ++oo)
#pragma unroll
      for (int q = 0; q < 4; ++q)
        *(u4v*)(smem + (tid * 2 + oo) * 80 + q * 16) =
            *(const u4v*)(Ptb + (size_t)(tid * 2 + oo) * 512 + h * 64 + q * 16);
    __syncthreads();                         // publish
#pragma unroll
    for (int to = 0; to < 32; ++to) {
      s8v afrag = *(const s8v*)(smem + (to * 16 + l16) * 80 + g * 16);
      acc2[to] = __builtin_amdgcn_mfma_f32_16x16x32_bf16(afrag, bfrag, acc2[to], 0, 0, 0);
    }
  }

  // ---- epilogue: +residual (bo folded into Pt), LN in registers (R5 exact) --
  float s1 = 0.f, s2 = 0.f;
#pragma unroll
  for (int to = 0; to < 32; ++to) {
    float4 xv = *(const float4*)&xr[to * 16 + 4 * g];
    acc2[to][0] += xv.x; acc2[to][1] += xv.y;
    acc2[to][2] += xv.z; acc2[to][3] += xv.w;
    s1 += (acc2[to][0] + acc2[to][1]) + (acc2[to][2] + acc2[to][3]);
    s2 += (acc2[to][0] * acc2[to][0] + acc2[to][1] * acc2[to][1]) +
          (acc2[to][2] * acc2[to][2] + acc2[to][3] * acc2[to][3]);
  }
  s1 += __shfl_xor(s1, 16); s2 += __shfl_xor(s2, 16);
  s1 += __shfl_xor(s1, 32); s2 += __shfl_xor(s2, 32);
  const float mean = s1 * (1.f / 512.f);
  const float var = s2 * (1.f / 512.f) - mean * mean;
  const float rstd = rsqrtf(var + 1e-5f);
#pragma unroll
  for (int to = 0; to < 32; ++to) {
    float4 wv = *(const float4*)&lnw[to * 16 + 4 * g];
    float4 bv = *(const float4*)&lnb[to * 16 + 4 * g];
    acc2[to][0] = (acc2[to][0] - mean) * rstd * wv.x + bv.x;
    acc2[to][1] = (acc2[to][1] - mean) * rstd * wv.y + bv.y;
    acc2[to][2] = (acc2[to][2] - mean) * rstd * wv.z + bv.z;
    acc2[to][3] = (acc2[to][3] - mean) * rstd * wv.w + bv.w;
  }

  // ---- store via LDS windows (R5 exact) ----
  const int prow = tid >> 7;               // 0..1
  const int pc = (tid & 127) * 4;          // float col within row
  for (int j = 0; j < 4; ++j) {
    __syncthreads();                       // window free / phase-2 reads done
    if (w == j) {
#pragma unroll
      for (int to = 0; to < 32; ++to)
        *(f4v*)&yb[l16 * 520 + to * 16 + 4 * g] = acc2[to];
    }
    __syncthreads();                       // publish
#pragma unroll
    for (int p = 0; p < 8; ++p)
      *(float4*)&y[(n0 + j * 16 + p * 2 + prow) * HH + pc] =
          *(const float4*)&yb[(p * 2 + prow) * 520 + pc];
  }
}

// ---------------------------------------------------------------------------
extern "C" void kernel_launch(void* const* d_in, const int* in_sizes, int n_in,
                              void* d_out, int out_size, void* d_ws, size_t ws_size,
                              hipStream_t stream) {
  const float* x    = (const float*)d_in[0];
  const float* cent = (const float*)d_in[1];
  const float* Wq   = (const float*)d_in[2];
  const float* bq   = (const float*)d_in[3];
  const float* Wk   = (const float*)d_in[4];
  const float* bk   = (const float*)d_in[5];
  const float* Wv   = (const float*)d_in[6];
  const float* bv   = (const float*)d_in[7];
  const float* Wo   = (const float*)d_in[8];
  const float* bo   = (const float*)d_in[9];
  const float* lnw  = (const float*)d_in[10];
  const float* lnb  = (const float*)d_in[11];
  float* ws = (float*)d_ws;
  float* y  = (float*)d_out;

  hipMemsetAsync(ws, 0, (16384 + 32) * sizeof(float), stream);
  k_km<<<512, 512, 0, stream>>>(x, cent, ws + WS_SUMS, ws + WS_COUNTS);
  k_upd<<<64, 256, 0, stream>>>(cent, ws + WS_SUMS, ws + WS_COUNTS, ws + WS_UPD);
  k_kv<<<128, 256, 0, stream>>>(ws + WS_UPD, Wk, bk, Wv, bv,
                                ws + WS_KBUF, ws + WS_VBUF);
  k_msp<<<1025, 256, 0, stream>>>(Wq, bq, ws + WS_KBUF, ws + WS_VBUF, Wo, bo,
                                  (unsigned short*)(ws + WS_MT), ws + WS_SB,
                                  (unsigned short*)(ws + WS_PT));
  k_main<<<4096, 256, 0, stream>>>(x, (const unsigned short*)(ws + WS_MT),
                                   ws + WS_SB, (const unsigned short*)(ws + WS_PT),
                                   lnw, lnb, y);
}

// Round 7
// 1381.240 us; speedup vs baseline: 1.9159x; 1.0955x over previous
//
#include <hip/hip_runtime.h>

#define NN 262144
#define HH 512
#define CC 32
#define MOMF 0.99f

// ws layout (float offsets) — R2/R5-proven region sizes.
#define WS_SUMS   0
#define WS_COUNTS 16384
#define WS_UPD    16416
#define WS_KBUF   32800
#define WS_VBUF   49184
#define WS_SB     65568
#define WS_MT     65824    // ushort[256*512] (bf16)
#define WS_PT     131360   // ushort[512*256] (bf16)

typedef __attribute__((ext_vector_type(8))) short s8v;
typedef __attribute__((ext_vector_type(4))) float f4v;
typedef __attribute__((ext_vector_type(4))) unsigned int u4v;

static __device__ __forceinline__ unsigned short f2bf(float f) {
  unsigned int u = __float_as_uint(f);
  u += 0x7FFFu + ((u >> 16) & 1u);   // round-to-nearest-even
  return (unsigned short)(u >> 16);
}
static __device__ __forceinline__ unsigned int pk2bf(float a, float b) {
  return (unsigned int)f2bf(a) | ((unsigned int)f2bf(b) << 16);
}

// ---------------------------------------------------------------------------
// Kernel 1 (fused k-means step, MFMA assignment):
// setup: cent -> LDS bf16 [32][520] + cn[c]=||c||^2 (fp32, from global)
// phase A (x4 passes of 128 nodes): S^T[c][node] = cent x^T via
//   mfma_16x16x32_bf16 (k_main-phase1-proven fragment pattern), then
//   argmin_c(cn[c]-2s) via in-lane + shfl_xor(16/32) lexicographic reduce.
// phase B: verbatim R6 (global x re-read, LDS atomic accumulate, flush).
// LDS: union region 65536B (phase A: clbf 33280 + scratch @40960;
//      phase B: fp32 sums buf) + cn 128 + sa 512 + lc 128 = 66304B.
// ---------------------------------------------------------------------------
__global__ __launch_bounds__(512) void k_km(const float* __restrict__ x,
                                            const float* __restrict__ cent,
                                            float* __restrict__ gsums,
                                            float* __restrict__ gcounts) {
  __shared__ __align__(16) unsigned char smem[66304];
  unsigned short* clbf = (unsigned short*)smem;        // [32][520] bf16
  float* scratch = (float*)(smem + 40960);             // setup only
  float* buf = (float*)smem;                           // phase B sums [32][512]
  float* cnS = (float*)(smem + 65536);                 // 32 floats
  unsigned char* sa = smem + 65664;                    // 512 assignments
  float* lc = (float*)(smem + 66176);                  // 32 counts

  const int tid = threadIdx.x;
  const int w = tid >> 6, l = tid & 63;
  const int l16 = l & 15, g = l >> 4;

  // ---- setup: stage cent bf16 + per-thread partial ||c||^2 ----
  {
    const int r = tid >> 4, colbase = (tid & 15) * 32;
#pragma unroll
    for (int q = 0; q < 4; ++q) {
      float4 a = *(const float4*)&cent[r * HH + colbase + q * 8];
      float4 b = *(const float4*)&cent[r * HH + colbase + q * 8 + 4];
      u4v p;
      p[0] = pk2bf(a.x, a.y); p[1] = pk2bf(a.z, a.w);
      p[2] = pk2bf(b.x, b.y); p[3] = pk2bf(b.z, b.w);
      *(u4v*)((unsigned char*)clbf + r * 1040 + (colbase + q * 8) * 2) = p;
    }
    const int c = tid >> 4, kk = tid & 15;
    float p = 0.f;
    for (int m = 0; m < 32; ++m) { float v = cent[c * HH + kk + 16 * m]; p += v * v; }
    scratch[tid] = p;
  }
  __syncthreads();
  if (tid < CC) {
    float s = 0.f;
    for (int m = 0; m < 16; ++m) s += scratch[tid * 16 + m];
    cnS[tid] = s;
  }
  __syncthreads();

  // hoist this lane's 8 cn values (c = tc*16 + 4g + r)
  float cnr[8];
#pragma unroll
  for (int tc = 0; tc < 2; ++tc)
#pragma unroll
    for (int r = 0; r < 4; ++r) cnr[tc * 4 + r] = cnS[tc * 16 + 4 * g + r];

  // ---- phase A: 4 passes x 128 nodes, MFMA scores + argmin ----
  for (int pass = 0; pass < 4; ++pass) {
    const int nodeloc = pass * 128 + w * 16 + l16;
    const float* xr = x + ((size_t)blockIdx.x * 512 + nodeloc) * HH;
    f4v acc[2];
    acc[0] = (f4v){0.f, 0.f, 0.f, 0.f};
    acc[1] = (f4v){0.f, 0.f, 0.f, 0.f};
    for (int kk = 0; kk < 16; ++kk) {
      float4 xa = *(const float4*)&xr[kk * 32 + g * 8];
      float4 xb = *(const float4*)&xr[kk * 32 + g * 8 + 4];
      s8v bfrag;
      bfrag[0] = (short)f2bf(xa.x); bfrag[1] = (short)f2bf(xa.y);
      bfrag[2] = (short)f2bf(xa.z); bfrag[3] = (short)f2bf(xa.w);
      bfrag[4] = (short)f2bf(xb.x); bfrag[5] = (short)f2bf(xb.y);
      bfrag[6] = (short)f2bf(xb.z); bfrag[7] = (short)f2bf(xb.w);
#pragma unroll
      for (int tc = 0; tc < 2; ++tc) {
        s8v afrag = *(const s8v*)((unsigned char*)clbf +
                                  (tc * 16 + l16) * 1040 + kk * 64 + g * 16);
        acc[tc] = __builtin_amdgcn_mfma_f32_16x16x32_bf16(afrag, bfrag, acc[tc], 0, 0, 0);
      }
    }
    // argmin (first-min on ties): in-lane ascending c order, then xor16/32
    float bv = 3.4e38f; int bi = 0;
#pragma unroll
    for (int tc = 0; tc < 2; ++tc)
#pragma unroll
      for (int r = 0; r < 4; ++r) {
        const int c = tc * 16 + 4 * g + r;
        const float v = cnr[tc * 4 + r] - 2.f * acc[tc][r];
        if (v < bv) { bv = v; bi = c; }
      }
#pragma unroll
    for (int m = 16; m <= 32; m <<= 1) {
      const float ov = __shfl_xor(bv, m);
      const int oi = __shfl_xor(bi, m);
      if (ov < bv || (ov == bv && oi < bi)) { bv = ov; bi = oi; }
    }
    if (l < 16) sa[nodeloc] = (unsigned char)bi;
  }
  __syncthreads();                     // clbf reads + sa writes done

  // ---- phase B: accumulate (R6-verbatim) ----
  for (int i = tid; i < CC * HH; i += 512) buf[i] = 0.f;
  if (tid < CC) lc[tid] = 0.f;
  __syncthreads();

  const int wave = tid >> 6, lane = tid & 63;
  const int nb = blockIdx.x * 512 + wave * 64;
  for (int it = 0; it < 64; ++it) {
    const int a = (int)sa[wave * 64 + it];
    const float* xp = x + (size_t)(nb + it) * HH;
    float v[8];
#pragma unroll
    for (int j = 0; j < 8; ++j) v[j] = xp[j * 64 + lane];
    if (lane == 0) atomicAdd(&lc[a], 1.f);
#pragma unroll
    for (int j = 0; j < 8; ++j) atomicAdd(&buf[a * HH + j * 64 + lane], v[j]);
  }
  __syncthreads();
  for (int i = tid; i < CC * HH; i += 512) atomicAdd(&gsums[i], buf[i]);
  if (tid < CC) atomicAdd(&gcounts[tid], lc[tid]);
}

// ---------------------------------------------------------------------------
// Kernel 3: EMA centroid update — R2 exact
// ---------------------------------------------------------------------------
__global__ void k_upd(const float* __restrict__ cent, const float* __restrict__ sums,
                      const float* __restrict__ counts, float* __restrict__ upd) {
  const int i = blockIdx.x * 256 + threadIdx.x;   // 16384
  const int c = i >> 9;
  const float cnt = counts[c];
  const float mean = sums[i] / fmaxf(cnt, 1.f);
  upd[i] = (cnt > 0.f) ? (MOMF * cent[i] + (1.f - MOMF) * mean) : cent[i];
}

// ---------------------------------------------------------------------------
// Kernel 4: k = upd@Wk + bk ; v = upd@Wv + bv   (32x512 each) — R2 exact
// ---------------------------------------------------------------------------
__global__ void k_kv(const float* __restrict__ upd,
                     const float* __restrict__ Wk, const float* __restrict__ bk,
                     const float* __restrict__ Wv, const float* __restrict__ bv,
                     float* __restrict__ kbuf, float* __restrict__ vbuf) {
  const int o = blockIdx.x * 256 + threadIdx.x;   // 0..32767
  const int sel = o >> 14;
  const int idx = o & 16383;
  const int c = idx >> 9, j = idx & 511;
  const float* W = sel ? Wv : Wk;
  const float* b = sel ? bv : bk;
  const float* u = upd + c * HH;
  float s = b[j];
  for (int i = 0; i < HH; ++i) s += u[i] * W[i * HH + j];
  (sel ? vbuf : kbuf)[idx] = s;
}

// ---------------------------------------------------------------------------
// Kernel 5: Mt (bf16, row-major transposed), sb, Pt (bf16, +bo/8) — R2 exact
// ---------------------------------------------------------------------------
__global__ void k_msp(const float* __restrict__ Wq, const float* __restrict__ bq,
                      const float* __restrict__ kbuf, const float* __restrict__ vbuf,
                      const float* __restrict__ Wo, const float* __restrict__ bo,
                      unsigned short* __restrict__ Mt, float* __restrict__ sb,
                      unsigned short* __restrict__ Pt) {
  const int b = blockIdx.x, t = threadIdx.x;
  const float scale = 0.125f;   // 1/sqrt(64)
  if (b < 512) {
    const int o = b * 256 + t;          // hc*512 + i
    const int hc = o >> 9, i = o & 511;
    const int h = hc >> 5, c = hc & 31;
    const float* wq = Wq + i * HH + h * 64;
    const float* kr = kbuf + c * HH + h * 64;
    float s = 0.f;
#pragma unroll
    for (int d = 0; d < 64; ++d) s += wq[d] * kr[d];
    Mt[o] = f2bf(s * scale);
  } else if (b < 1024) {
    const int o = b - 512;              // output col (0..511)
    const int hc = t;                   // 0..255
    const int h = hc >> 5, c = hc & 31;
    const float* vr = vbuf + c * HH + h * 64;
    const float* wo = Wo + h * 64 * HH + o;
    float s = 0.f;
#pragma unroll
    for (int d = 0; d < 64; ++d) s += vr[d] * wo[d * HH];
    Pt[o * 256 + hc] = f2bf(s + bo[o] * scale);
  } else if (t < 256) {
    const int h = t >> 5, c = t & 31;
    const float* kr = kbuf + c * HH + h * 64;
    const float* bqp = bq + h * 64;
    float s = 0.f;
#pragma unroll
    for (int d = 0; d < 64; ++d) s += bqp[d] * kr[d];
    sb[t] = s * scale;
  }
}

// ---------------------------------------------------------------------------
// Kernel 6 (main, MFMA): R6 exact (LDS-staged A-frags, reg softmax/LN,
// windowed coalesced stores).
// ---------------------------------------------------------------------------
__global__ __launch_bounds__(256, 2) void k_main(
    const float* __restrict__ x, const unsigned short* __restrict__ Mt,
    const float* __restrict__ sb, const unsigned short* __restrict__ Pt,
    const float* __restrict__ lnw, const float* __restrict__ lnb,
    float* __restrict__ y) {
  __shared__ __align__(16) unsigned char smem[40960];  // stage / store window
  float* yb = (float*)smem;                            // [16][520] fp32 window
  const unsigned char* Mtb = (const unsigned char*)Mt;
  const unsigned char* Ptb = (const unsigned char*)Pt;
  const int tid = threadIdx.x;
  const int w = tid >> 6, l = tid & 63;
  const int l16 = l & 15, g = l >> 4;            // lane column / k-group
  const size_t n0 = (size_t)blockIdx.x * 64;
  const size_t xrow = n0 + w * 16 + l16;
  const float* xr = x + xrow * HH;

  // ---- phase 1: S^T[score_col=16tc+4g+r][xrow] ----
  f4v acc1[16];
#pragma unroll
  for (int tc = 0; tc < 16; ++tc)
    acc1[tc] = *(const f4v*)&sb[tc * 16 + 4 * g];

  for (int kk = 0; kk < 16; ++kk) {
    float4 xa = *(const float4*)&xr[kk * 32 + g * 8];
    float4 xb = *(const float4*)&xr[kk * 32 + g * 8 + 4];
    __syncthreads();                         // prev slice reads done
#pragma unroll
    for (int r = 0; r < 4; ++r)
      *(u4v*)(smem + tid * 80 + r * 16) =
          *(const u4v*)(Mtb + tid * 1024 + kk * 64 + r * 16);
    __syncthreads();                         // publish
    s8v bfrag;
    bfrag[0] = (short)f2bf(xa.x); bfrag[1] = (short)f2bf(xa.y);
    bfrag[2] = (short)f2bf(xa.z); bfrag[3] = (short)f2bf(xa.w);
    bfrag[4] = (short)f2bf(xb.x); bfrag[5] = (short)f2bf(xb.y);
    bfrag[6] = (short)f2bf(xb.z); bfrag[7] = (short)f2bf(xb.w);
#pragma unroll
    for (int tc = 0; tc < 16; ++tc) {
      s8v afrag = *(const s8v*)(smem + (tc * 16 + l16) * 80 + g * 16);
      acc1[tc] = __builtin_amdgcn_mfma_f32_16x16x32_bf16(afrag, bfrag, acc1[tc], 0, 0, 0);
    }
  }

  // ---- softmax per head h (cols 32h..32h+31): 8 in-lane + xor16/xor32 ----
  unsigned int apk[16][2];
#pragma unroll
  for (int h = 0; h < 8; ++h) {
    f4v s0 = acc1[2 * h], s1 = acc1[2 * h + 1];
    float m = fmaxf(fmaxf(fmaxf(s0[0], s0[1]), fmaxf(s0[2], s0[3])),
                    fmaxf(fmaxf(s1[0], s1[1]), fmaxf(s1[2], s1[3])));
    m = fmaxf(m, __shfl_xor(m, 16));
    m = fmaxf(m, __shfl_xor(m, 32));
    float e0 = __expf(s0[0] - m), e1 = __expf(s0[1] - m);
    float e2 = __expf(s0[2] - m), e3 = __expf(s0[3] - m);
    float e4 = __expf(s1[0] - m), e5 = __expf(s1[1] - m);
    float e6 = __expf(s1[2] - m), e7 = __expf(s1[3] - m);
    float sum = ((e0 + e1) + (e2 + e3)) + ((e4 + e5) + (e6 + e7));
    sum += __shfl_xor(sum, 16);
    sum += __shfl_xor(sum, 32);
    const float inv = 1.f / sum;
    apk[2 * h][0] = pk2bf(e0 * inv, e1 * inv);
    apk[2 * h][1] = pk2bf(e2 * inv, e3 * inv);
    apk[2 * h + 1][0] = pk2bf(e4 * inv, e5 * inv);
    apk[2 * h + 1][1] = pk2bf(e6 * inv, e7 * inv);
  }

  // ---- phase 2: C2^T[o=16to+4g+r][xrow] = sum_h Pt[o][32h..] attn^T ----
  f4v acc2[32];
#pragma unroll
  for (int to = 0; to < 32; ++to) acc2[to] = (f4v){0.f, 0.f, 0.f, 0.f};

  for (int h = 0; h < 8; ++h) {
    unsigned int dw[4];
#pragma unroll
    for (int d = 0; d < 4; ++d) {
      const int gsrc = 2 * (g & 1) + (d >> 1);
      const int src = l16 + 16 * gsrc;
      unsigned int t0 = (unsigned int)__shfl((int)apk[2 * h][d & 1], src, 64);
      unsigned int t1 = (unsigned int)__shfl((int)apk[2 * h + 1][d & 1], src, 64);
      dw[d] = (g < 2) ? t0 : t1;
    }
    u4v bu; bu[0] = dw[0]; bu[1] = dw[1]; bu[2] = dw[2]; bu[3] = dw[3];
    s8v bfrag = __builtin_bit_cast(s8v, bu);
    __syncthreads();                         // prev slice reads done
#pragma unroll
    for (int oo = 0; oo < 2; ++oo)
#pragma unroll
      for (int q = 0; q < 4; ++q)
        *(u4v*)(smem + (tid * 2 + oo) * 80 + q * 16) =
            *(const u4v*)(Ptb + (size_t)(tid * 2 + oo) * 512 + h * 64 + q * 16);
    __syncthreads();                         // publish
#pragma unroll
    for (int to = 0; to < 32; ++to) {
      s8v afrag = *(const s8v*)(smem + (to * 16 + l16) * 80 + g * 16);
      acc2[to] = __builtin_amdgcn_mfma_f32_16x16x32_bf16(afrag, bfrag, acc2[to], 0, 0, 0);
    }
  }

  // ---- epilogue: +residual (bo folded into Pt), LN in registers ----
  float s1 = 0.f, s2 = 0.f;
#pragma unroll
  for (int to = 0; to < 32; ++to) {
    float4 xv = *(const float4*)&xr[to * 16 + 4 * g];
    acc2[to][0] += xv.x; acc2[to][1] += xv.y;
    acc2[to][2] += xv.z; acc2[to][3] += xv.w;
    s1 += (acc2[to][0] + acc2[to][1]) + (acc2[to][2] + acc2[to][3]);
    s2 += (acc2[to][0] * acc2[to][0] + acc2[to][1] * acc2[to][1]) +
          (acc2[to][2] * acc2[to][2] + acc2[to][3] * acc2[to][3]);
  }
  s1 += __shfl_xor(s1, 16); s2 += __shfl_xor(s2, 16);
  s1 += __shfl_xor(s1, 32); s2 += __shfl_xor(s2, 32);
  const float mean = s1 * (1.f / 512.f);
  const float var = s2 * (1.f / 512.f) - mean * mean;
  const float rstd = rsqrtf(var + 1e-5f);
#pragma unroll
  for (int to = 0; to < 32; ++to) {
    float4 wv = *(const float4*)&lnw[to * 16 + 4 * g];
    float4 bv = *(const float4*)&lnb[to * 16 + 4 * g];
    acc2[to][0] = (acc2[to][0] - mean) * rstd * wv.x + bv.x;
    acc2[to][1] = (acc2[to][1] - mean) * rstd * wv.y + bv.y;
    acc2[to][2] = (acc2[to][2] - mean) * rstd * wv.z + bv.z;
    acc2[to][3] = (acc2[to][3] - mean) * rstd * wv.w + bv.w;
  }

  // ---- store via LDS windows (R5/R6 exact) ----
  const int prow = tid >> 7;               // 0..1
  const int pc = (tid & 127) * 4;          // float col within row
  for (int j = 0; j < 4; ++j) {
    __syncthreads();                       // window free / phase-2 reads done
    if (w == j) {
#pragma unroll
      for (int to = 0; to < 32; ++to)
        *(f4v*)&yb[l16 * 520 + to * 16 + 4 * g] = acc2[to];
    }
    __syncthreads();                       // publish
#pragma unroll
    for (int p = 0; p < 8; ++p)
      *(float4*)&y[(n0 + j * 16 + p * 2 + prow) * HH + pc] =
          *(const float4*)&yb[(p * 2 + prow) * 520 + pc];
  }
}

// ---------------------------------------------------------------------------
extern "C" void kernel_launch(void* const* d_in, const int* in_sizes, int n_in,
                              void* d_out, int out_size, void* d_ws, size_t ws_size,
                              hipStream_t stream) {
  const float* x    = (const float*)d_in[0];
  const float* cent = (const float*)d_in[1];
  const float* Wq   = (const float*)d_in[2];
  const float* bq   = (const float*)d_in[3];
  const float* Wk   = (const float*)d_in[4];
  const float* bk   = (const float*)d_in[5];
  const float* Wv   = (const float*)d_in[6];
  const float* bv   = (const float*)d_in[7];
  const float* Wo   = (const float*)d_in[8];
  const float* bo   = (const float*)d_in[9];
  const float* lnw  = (const float*)d_in[10];
  const float* lnb  = (const float*)d_in[11];
  float* ws = (float*)d_ws;
  float* y  = (float*)d_out;

  hipMemsetAsync(ws, 0, (16384 + 32) * sizeof(float), stream);
  k_km<<<512, 512, 0, stream>>>(x, cent, ws + WS_SUMS, ws + WS_COUNTS);
  k_upd<<<64, 256, 0, stream>>>(cent, ws + WS_SUMS, ws + WS_COUNTS, ws + WS_UPD);
  k_kv<<<128, 256, 0, stream>>>(ws + WS_UPD, Wk, bk, Wv, bv,
                                ws + WS_KBUF, ws + WS_VBUF);
  k_msp<<<1025, 256, 0, stream>>>(Wq, bq, ws + WS_KBUF, ws + WS_VBUF, Wo, bo,
                                  (unsigned short*)(ws + WS_MT), ws + WS_SB,
                                  (unsigned short*)(ws + WS_PT));
  k_main<<<4096, 256, 0, stream>>>(x, (const unsigned short*)(ws + WS_MT),
                                   ws + WS_SB, (const unsigned short*)(ws + WS_PT),
                                   lnw, lnb, y);
}